// Round 1
// baseline (648.540 us; speedup 1.0000x reference)
//
#include <hip/hip_runtime.h>
#include <math.h>

#define N_NODES 100000
#define N_EDGES 3200000
#define N_FEAT  500
#define NF4     125      // N_FEAT / 4
#define N_HID   16
#define N_CLS   7

#define BKT_SHIFT 7
#define BKT_SIZE  128
#define NBKT      782            // ceil(100000/128)
#define NBLK_BIN  256            // edge-chunk blocks for hist/binpass
#define EDGES_PER_BLK 12500      // 256 * 12500 = 3.2M exactly
#define COUNTS_LEN (NBKT * NBLK_BIN)   // 200192
#define NBLK_SCANA (COUNTS_LEN / 256)  // 782 exactly
#define SBUF_CAP  5632           // max edges/bucket (mean 4092, sd 64 -> 24 sd)

// ---------------- workspace layout (dword offsets) --------------------------
#define OFF_DINV   0            // 100000 f
#define OFF_COUNTS 100000       // 200192 i
#define OFF_BSUM   300192       // 1024 i
#define OFF_ROWP   301216       // 100001 i (+3 pad)
#define OFF_BINNED 401220       // 3200000 u32 (src | dst_local<<17)
#define OFF_SORTED 3601220      // 3200000 u32 (src, grouped per dst node)
#define OFF_M1S    6801220      // 1600000 ushort bf16 (m1*dinv), 32 B/row
#define OFF_M2S    7601220      // 800000 ushort bf16 (m2*dinv), 16 B/row (pad 8th)
// total 8,001,220 dwords = 32.0 MB

// ------------------------------------------------------------- bf16 helpers
__device__ inline unsigned short f2bf(float f) {
    unsigned int u = __float_as_uint(f);
    return (unsigned short)((u + 0x7FFF + ((u >> 16) & 1)) >> 16);
}
__device__ inline float bf2f(unsigned short h) {
    return __uint_as_float((unsigned int)h << 16);
}

// ------------------------------------------------------------- pass 1: hist
__global__ void hist(const int* __restrict__ dst, int* __restrict__ counts) {
    __shared__ int cnt[NBKT];
    int t = threadIdx.x, b = blockIdx.x;
    for (int i = t; i < NBKT; i += 256) cnt[i] = 0;
    __syncthreads();
    int e0 = b * EDGES_PER_BLK;
    for (int e = e0 + t; e < e0 + EDGES_PER_BLK; e += 256)
        atomicAdd(&cnt[dst[e] >> BKT_SHIFT], 1);
    __syncthreads();
    for (int i = t; i < NBKT; i += 256)
        counts[i * NBLK_BIN + b] = cnt[i];
}

// ------------------------------------------------------------- scan chain
__global__ void scanA(int* __restrict__ counts, int* __restrict__ bsum) {
    __shared__ int s[256];
    int t = threadIdx.x;
    int i = blockIdx.x * 256 + t;
    int v = counts[i];
    s[t] = v;
    __syncthreads();
    for (int off = 1; off < 256; off <<= 1) {
        int a = (t >= off) ? s[t - off] : 0;
        __syncthreads();
        s[t] += a;
        __syncthreads();
    }
    counts[i] = s[t] - v;
    if (t == 255) bsum[blockIdx.x] = s[255];
}

__global__ void scanB(int* __restrict__ bsum) {
    __shared__ int s[1024];
    int t = threadIdx.x;
    int v = (t < NBLK_SCANA) ? bsum[t] : 0;
    s[t] = v;
    __syncthreads();
    for (int off = 1; off < 1024; off <<= 1) {
        int a = (t >= off) ? s[t - off] : 0;
        __syncthreads();
        s[t] += a;
        __syncthreads();
    }
    if (t < NBLK_SCANA) bsum[t] = s[t] - v;
}

__global__ void scanC(int* __restrict__ counts, const int* __restrict__ bsum) {
    int i = blockIdx.x * 256 + threadIdx.x;
    counts[i] += bsum[i >> 8];
}

// ------------------------------------------------------------- pass 2: bin
__global__ void binpass(const int* __restrict__ src, const int* __restrict__ dst,
                        const int* __restrict__ counts, unsigned int* __restrict__ binned) {
    __shared__ int cur[NBKT];
    int t = threadIdx.x, b = blockIdx.x;
    for (int i = t; i < NBKT; i += 256) cur[i] = counts[i * NBLK_BIN + b];
    __syncthreads();
    int e0 = b * EDGES_PER_BLK;
    for (int e = e0 + t; e < e0 + EDGES_PER_BLK; e += 256) {
        int d = dst[e];
        int pos = atomicAdd(&cur[d >> BKT_SHIFT], 1);
        binned[pos] = (unsigned int)src[e] | ((unsigned int)(d & (BKT_SIZE - 1)) << 17);
    }
}

// ---------------------- pass 3: per-bucket sort by node + rowptr + dinv
__global__ __launch_bounds__(512) void sortpass(const unsigned int* __restrict__ binned,
        const int* __restrict__ counts, unsigned int* __restrict__ sorted,
        int* __restrict__ rowptr, float* __restrict__ dinv) {
    __shared__ int cnt[BKT_SIZE];
    __shared__ int sc[BKT_SIZE];
    __shared__ int cur[BKT_SIZE];
    __shared__ unsigned int sbuf[SBUF_CAP];
    int t = threadIdx.x, b = blockIdx.x;
    int beg = counts[b * NBLK_BIN];
    int end = (b < NBKT - 1) ? counts[(b + 1) * NBLK_BIN] : N_EDGES;
    if (t < BKT_SIZE) cnt[t] = 0;
    __syncthreads();
    for (int e = beg + t; e < end; e += 512)
        atomicAdd(&cnt[(binned[e] >> 17) & (BKT_SIZE - 1)], 1);
    __syncthreads();
    int v = (t < BKT_SIZE) ? cnt[t] : 0;
    if (t < BKT_SIZE) sc[t] = v;
    __syncthreads();
    for (int off = 1; off < BKT_SIZE; off <<= 1) {
        int a = (t < BKT_SIZE && t >= off) ? sc[t - off] : 0;
        __syncthreads();
        if (t < BKT_SIZE) sc[t] += a;
        __syncthreads();
    }
    if (t < BKT_SIZE) {
        cur[t] = sc[t] - v;                    // exclusive, bucket-local
        int g = b * BKT_SIZE + t;
        if (g < N_NODES) {
            rowptr[g] = beg + sc[t] - v;
            dinv[g] = rsqrtf((float)v + 1.0f);  // +1 self loop
        }
    }
    if (b == 0 && t == 0) rowptr[N_NODES] = N_EDGES;
    __syncthreads();
    for (int e = beg + t; e < end; e += 512) {
        unsigned int u = binned[e];
        int pos = atomicAdd(&cur[(u >> 17) & (BKT_SIZE - 1)], 1);
        if (pos < SBUF_CAP) sbuf[pos] = u & 0x1FFFF;
    }
    __syncthreads();
    int n = end - beg;
    for (int i = t; i < n; i += 512) sorted[beg + i] = sbuf[i];
}

// ------------------------------------------- m1s = bf16((x @ W1) * dinv)
// Redesign: lane-owns-rows, reduction axis in-lane (no shuffle chains).
// 782 blocks x 256 thr; wave w = feature slice q (32/31/31/31 float4s);
// each lane streams 2 rows with 2x16 fp32 register accumulators; W1 lives
// in LDS and is read wave-uniform (broadcast, conflict-free); partials
// combined once per block through a +65-stride LDS buffer aliasing W.
#define G1_ROWS 128
#define G1_NBLK 782   // ceil(100000/128)

#define G1_FF(fa, fb, kk, ff) { \
    const float4* wp_ = sW4 + (kk) * 16 + (ff) * 4; \
    const float4 w0_ = wp_[0], w1_ = wp_[1], w2_ = wp_[2], w3_ = wp_[3]; \
    accA0.x += (fa) * w0_.x; accA0.y += (fa) * w0_.y; accA0.z += (fa) * w0_.z; accA0.w += (fa) * w0_.w; \
    accA1.x += (fa) * w1_.x; accA1.y += (fa) * w1_.y; accA1.z += (fa) * w1_.z; accA1.w += (fa) * w1_.w; \
    accA2.x += (fa) * w2_.x; accA2.y += (fa) * w2_.y; accA2.z += (fa) * w2_.z; accA2.w += (fa) * w2_.w; \
    accA3.x += (fa) * w3_.x; accA3.y += (fa) * w3_.y; accA3.z += (fa) * w3_.z; accA3.w += (fa) * w3_.w; \
    accB0.x += (fb) * w0_.x; accB0.y += (fb) * w0_.y; accB0.z += (fb) * w0_.z; accB0.w += (fb) * w0_.w; \
    accB1.x += (fb) * w1_.x; accB1.y += (fb) * w1_.y; accB1.z += (fb) * w1_.z; accB1.w += (fb) * w1_.w; \
    accB2.x += (fb) * w2_.x; accB2.y += (fb) * w2_.y; accB2.z += (fb) * w2_.z; accB2.w += (fb) * w2_.w; \
    accB3.x += (fb) * w3_.x; accB3.y += (fb) * w3_.y; accB3.z += (fb) * w3_.z; accB3.w += (fb) * w3_.w; \
}

#define G1_F4(xa, xb, kk) \
    G1_FF((xa).x, (xb).x, (kk), 0) \
    G1_FF((xa).y, (xb).y, (kk), 1) \
    G1_FF((xa).z, (xb).z, (kk), 2) \
    G1_FF((xa).w, (xb).w, (kk), 3)

__global__ __launch_bounds__(256) void gemm1(const float* __restrict__ x,
                                             const float* __restrict__ W1,
                                             const float* __restrict__ dinv,
                                             unsigned short* __restrict__ m1s) {
    __shared__ float smem[G1_ROWS * 65];   // 33.3 KB: W1 (32 KB) then partials (aliased)
    const int t = threadIdx.x;
    const int b = blockIdx.x;

    // stage W1 (500x16 f32 = 2000 float4) into LDS, coalesced
    {
        const float4* w4 = (const float4*)W1;
        float4* s4 = (float4*)smem;
        for (int i = t; i < 2000; i += 256) s4[i] = w4[i];
    }
    __syncthreads();

    const int w = t >> 6;      // wave id == feature-slice q
    const int lane = t & 63;
    const int f0 = (w == 0) ? 0 : 32 + 31 * (w - 1);   // float4 slice start
    const int cnt = (w == 0) ? 32 : 31;                // slice length (32/31/31/31 = 125)

    const int rowA = b * G1_ROWS + lane;
    const int rowB = rowA + 64;
    const bool vA = rowA < N_NODES, vB = rowB < N_NODES;
    const float4* xA = (const float4*)x + (size_t)(vA ? rowA : 0) * NF4 + f0;
    const float4* xB = (const float4*)x + (size_t)(vB ? rowB : 0) * NF4 + f0;
    const float4* sW4 = (const float4*)smem;

    float4 accA0 = make_float4(0.f, 0.f, 0.f, 0.f), accA1 = accA0, accA2 = accA0, accA3 = accA0;
    float4 accB0 = accA0, accB1 = accA0, accB2 = accA0, accB3 = accA0;

    int i = 0;
    for (; i + 2 <= cnt; i += 2) {
        float4 a0 = xA[i], a1 = xA[i + 1];
        float4 b0 = xB[i], b1 = xB[i + 1];
        G1_F4(a0, b0, f0 + i)
        G1_F4(a1, b1, f0 + i + 1)
    }
    if (i < cnt) {
        float4 a0 = xA[i];
        float4 b0 = xB[i];
        G1_F4(a0, b0, f0 + i)
    }

    __syncthreads();   // everyone done reading W -> reuse smem for partials

    // partials: smem[row*65 + q*16 + j]; lane stride 65 => bank (lane+c)%32, conflict-free
    {
        float* pA = &smem[lane * 65 + w * 16];
        pA[0] = accA0.x; pA[1] = accA0.y; pA[2] = accA0.z; pA[3] = accA0.w;
        pA[4] = accA1.x; pA[5] = accA1.y; pA[6] = accA1.z; pA[7] = accA1.w;
        pA[8] = accA2.x; pA[9] = accA2.y; pA[10] = accA2.z; pA[11] = accA2.w;
        pA[12] = accA3.x; pA[13] = accA3.y; pA[14] = accA3.z; pA[15] = accA3.w;
        float* pB = &smem[(lane + 64) * 65 + w * 16];
        pB[0] = accB0.x; pB[1] = accB0.y; pB[2] = accB0.z; pB[3] = accB0.w;
        pB[4] = accB1.x; pB[5] = accB1.y; pB[6] = accB1.z; pB[7] = accB1.w;
        pB[8] = accB2.x; pB[9] = accB2.y; pB[10] = accB2.z; pB[11] = accB2.w;
        pB[12] = accB3.x; pB[13] = accB3.y; pB[14] = accB3.z; pB[15] = accB3.w;
    }
    __syncthreads();

    // combine 4 slices, scale by dinv, pack bf16, 16 B store per thread
    {
        const int r = t >> 1;
        const int j8 = (t & 1) * 8;
        const int g = b * G1_ROWS + r;
        if (g < N_NODES) {
            const float di = dinv[g];
            const float* pr = &smem[r * 65 + j8];
            float s0 = pr[0] + pr[16] + pr[32] + pr[48];
            float s1 = pr[1] + pr[17] + pr[33] + pr[49];
            float s2 = pr[2] + pr[18] + pr[34] + pr[50];
            float s3 = pr[3] + pr[19] + pr[35] + pr[51];
            float s4v = pr[4] + pr[20] + pr[36] + pr[52];
            float s5 = pr[5] + pr[21] + pr[37] + pr[53];
            float s6 = pr[6] + pr[22] + pr[38] + pr[54];
            float s7 = pr[7] + pr[23] + pr[39] + pr[55];
            unsigned int p0 = (unsigned int)f2bf(s0 * di) | ((unsigned int)f2bf(s1 * di) << 16);
            unsigned int p1 = (unsigned int)f2bf(s2 * di) | ((unsigned int)f2bf(s3 * di) << 16);
            unsigned int p2 = (unsigned int)f2bf(s4v * di) | ((unsigned int)f2bf(s5 * di) << 16);
            unsigned int p3 = (unsigned int)f2bf(s6 * di) | ((unsigned int)f2bf(s7 * di) << 16);
            *(uint4*)&m1s[(size_t)g * 16 + j8] = make_uint4(p0, p1, p2, p3);
        }
    }
}

// -------- layer-1 aggregate (register owner-computes) + bias + ReLU + h@W2
// 4 lanes per node; lane q owns features 4q..4q+3; per edge one uint2 (8B);
// the 4 lanes' loads form one 32B row segment. NO atomics.
__global__ __launch_bounds__(512) void agg1(const unsigned int* __restrict__ sorted,
        const int* __restrict__ rowptr, const float* __restrict__ dinv,
        const unsigned short* __restrict__ m1s, const float* __restrict__ b1,
        const float* __restrict__ W2, unsigned short* __restrict__ m2s) {
    __shared__ float acc[BKT_SIZE * 17];
    __shared__ float sW2[N_HID * N_CLS];
    __shared__ float sb1[N_HID];
    int t = threadIdx.x, b = blockIdx.x;
    if (t < N_HID * N_CLS) sW2[t] = W2[t];
    if (t < N_HID) sb1[t] = b1[t];
    int n = t >> 2, q = t & 3;
    int g = b * BKT_SIZE + n;
    float a0 = 0.f, a1 = 0.f, a2 = 0.f, a3 = 0.f;
    if (g < N_NODES) {
        int beg = rowptr[g], end = rowptr[g + 1];
        int p = beg;
        for (; p + 1 < end; p += 2) {
            unsigned int s0 = sorted[p], s1 = sorted[p + 1];
            uint2 w0 = *(const uint2*)&m1s[(size_t)s0 * 16 + q * 4];
            uint2 w1 = *(const uint2*)&m1s[(size_t)s1 * 16 + q * 4];
            a0 += __uint_as_float(w0.x << 16);
            a1 += __uint_as_float(w0.x & 0xFFFF0000u);
            a2 += __uint_as_float(w0.y << 16);
            a3 += __uint_as_float(w0.y & 0xFFFF0000u);
            a0 += __uint_as_float(w1.x << 16);
            a1 += __uint_as_float(w1.x & 0xFFFF0000u);
            a2 += __uint_as_float(w1.y << 16);
            a3 += __uint_as_float(w1.y & 0xFFFF0000u);
        }
        if (p < end) {
            unsigned int s0 = sorted[p];
            uint2 w0 = *(const uint2*)&m1s[(size_t)s0 * 16 + q * 4];
            a0 += __uint_as_float(w0.x << 16);
            a1 += __uint_as_float(w0.x & 0xFFFF0000u);
            a2 += __uint_as_float(w0.y << 16);
            a3 += __uint_as_float(w0.y & 0xFFFF0000u);
        }
    }
    float* ap = &acc[n * 17 + q * 4];
    ap[0] = a0; ap[1] = a1; ap[2] = a2; ap[3] = a3;
    __syncthreads();
    // h = relu(dinv_g * (acc + m1s_g) + b1), in place (stride 17)
    for (int idx = t; idx < BKT_SIZE * 16; idx += 512) {
        int nn = idx >> 4, jj = idx & 15;
        int gg = b * BKT_SIZE + nn;
        if (gg < N_NODES) {
            float di = dinv[gg];
            float hv = di * (acc[nn * 17 + jj] + bf2f(m1s[(size_t)gg * 16 + jj])) + sb1[jj];
            acc[nn * 17 + jj] = hv > 0.f ? hv : 0.f;
        }
    }
    __syncthreads();
    // m2s = bf16(dinv_g * (h @ W2)), stride 8, slot 7 = 0 pad
    for (int idx = t; idx < BKT_SIZE * 8; idx += 512) {
        int nn = idx >> 3, cc = idx & 7;
        int gg = b * BKT_SIZE + nn;
        if (gg < N_NODES) {
            float sum = 0.f;
            if (cc < N_CLS) {
#pragma unroll
                for (int jj = 0; jj < N_HID; ++jj) sum += acc[nn * 17 + jj] * sW2[jj * 7 + cc];
                sum *= dinv[gg];
            }
            m2s[(size_t)gg * 8 + cc] = f2bf(sum);
        }
    }
}

// -------- layer-2 aggregate (register owner-computes) + bias + log-softmax
// 2 lanes per node; lane q owns slots 4q..4q+3 (slot 7 = pad). NO atomics.
__global__ __launch_bounds__(256) void agg2(const unsigned int* __restrict__ sorted,
        const int* __restrict__ rowptr, const float* __restrict__ dinv,
        const unsigned short* __restrict__ m2s, const float* __restrict__ b2,
        float* __restrict__ out) {
    __shared__ float acc[BKT_SIZE * 9];
    int t = threadIdx.x, b = blockIdx.x;
    int n = t >> 1, q = t & 1;
    int g = b * BKT_SIZE + n;
    float a0 = 0.f, a1 = 0.f, a2 = 0.f, a3 = 0.f;
    if (g < N_NODES) {
        int beg = rowptr[g], end = rowptr[g + 1];
        int p = beg;
        for (; p + 1 < end; p += 2) {
            unsigned int s0 = sorted[p], s1 = sorted[p + 1];
            uint2 w0 = *(const uint2*)&m2s[(size_t)s0 * 8 + q * 4];
            uint2 w1 = *(const uint2*)&m2s[(size_t)s1 * 8 + q * 4];
            a0 += __uint_as_float(w0.x << 16);
            a1 += __uint_as_float(w0.x & 0xFFFF0000u);
            a2 += __uint_as_float(w0.y << 16);
            a3 += __uint_as_float(w0.y & 0xFFFF0000u);
            a0 += __uint_as_float(w1.x << 16);
            a1 += __uint_as_float(w1.x & 0xFFFF0000u);
            a2 += __uint_as_float(w1.y << 16);
            a3 += __uint_as_float(w1.y & 0xFFFF0000u);
        }
        if (p < end) {
            unsigned int s0 = sorted[p];
            uint2 w0 = *(const uint2*)&m2s[(size_t)s0 * 8 + q * 4];
            a0 += __uint_as_float(w0.x << 16);
            a1 += __uint_as_float(w0.x & 0xFFFF0000u);
            a2 += __uint_as_float(w0.y << 16);
            a3 += __uint_as_float(w0.y & 0xFFFF0000u);
        }
    }
    float* ap = &acc[n * 9 + q * 4];
    ap[0] = a0; ap[1] = a1; ap[2] = a2; ap[3] = a3;
    __syncthreads();
    int j = t & 7;
    for (int pass = 0; pass < 4; ++pass) {
        int nn = (t >> 3) + pass * 32;
        int gg = b * BKT_SIZE + nn;
        bool valid = (gg < N_NODES) && (j < N_CLS);
        float v = -1e30f;
        if (valid) {
            float di = dinv[gg];
            v = di * (acc[nn * 9 + j] + bf2f(m2s[(size_t)gg * 8 + j])) + b2[j];
        }
        float mx = v;
#pragma unroll
        for (int off = 1; off < 8; off <<= 1) mx = fmaxf(mx, __shfl_xor(mx, off, 8));
        float ex = valid ? expf(v - mx) : 0.f;
        float sum = ex;
#pragma unroll
        for (int off = 1; off < 8; off <<= 1) sum += __shfl_xor(sum, off, 8);
        float ls = mx + logf(sum);
        if (valid) out[(size_t)gg * 7 + j] = v - ls;
    }
}

// ----------------------------------------------------------------
extern "C" void kernel_launch(void* const* d_in, const int* in_sizes, int n_in,
                              void* d_out, int out_size, void* d_ws, size_t ws_size,
                              hipStream_t stream) {
    const float* x  = (const float*)d_in[0];
    const int*   ei = (const int*)d_in[1];
    const float* W1 = (const float*)d_in[2];
    const float* b1 = (const float*)d_in[3];
    const float* W2 = (const float*)d_in[4];
    const float* b2 = (const float*)d_in[5];
    float* out = (float*)d_out;
    char*  wsb = (char*)d_ws;   // needs 32.0 MB

    const int* src = ei;               // edge_index[0]
    const int* dst = ei + N_EDGES;     // edge_index[1]

    float*          dinv   = (float*)wsb + OFF_DINV;
    int*            counts = (int*)wsb + OFF_COUNTS;
    int*            bsum   = (int*)wsb + OFF_BSUM;
    int*            rowptr = (int*)wsb + OFF_ROWP;
    unsigned int*   binned = (unsigned int*)wsb + OFF_BINNED;
    unsigned int*   sorted = (unsigned int*)wsb + OFF_SORTED;
    unsigned short* m1s    = (unsigned short*)(wsb + (size_t)OFF_M1S * 4);
    unsigned short* m2s    = (unsigned short*)(wsb + (size_t)OFF_M2S * 4);

    hist     <<<NBLK_BIN, 256, 0, stream>>>(dst, counts);
    scanA    <<<NBLK_SCANA, 256, 0, stream>>>(counts, bsum);
    scanB    <<<1, 1024, 0, stream>>>(bsum);
    scanC    <<<NBLK_SCANA, 256, 0, stream>>>(counts, bsum);
    binpass  <<<NBLK_BIN, 256, 0, stream>>>(src, dst, counts, binned);
    sortpass <<<NBKT, 512, 0, stream>>>(binned, counts, sorted, rowptr, dinv);
    gemm1    <<<G1_NBLK, 256, 0, stream>>>(x, W1, dinv, m1s);
    agg1     <<<NBKT, 512, 0, stream>>>(sorted, rowptr, dinv, m1s, b1, W2, m2s);
    agg2     <<<NBKT, 256, 0, stream>>>(sorted, rowptr, dinv, m2s, b2, out);
}

// Round 2
// 520.636 us; speedup vs baseline: 1.2457x; 1.2457x over previous
//
#include <hip/hip_runtime.h>
#include <math.h>

#define N_NODES 100000
#define N_EDGES 3200000
#define N_FEAT  500
#define NF4     125      // N_FEAT / 4
#define N_HID   16
#define N_CLS   7

#define BKT_SHIFT 7
#define BKT_SIZE  128
#define NBKT      782            // ceil(100000/128)
#define NBLK_BIN  256            // edge-chunk blocks for hist/binpass
#define EDGES_PER_BLK 12500      // 256 * 12500 = 3.2M exactly
#define COUNTS_LEN (NBKT * NBLK_BIN)   // 200192
#define NBLK_SCANA (COUNTS_LEN / 256)  // 782 exactly
#define SBUF_CAP  5632           // max edges/bucket (mean 4092, sd 64 -> 24 sd)

// ---------------- workspace layout (dword offsets) --------------------------
#define OFF_DINV   0            // 100000 f
#define OFF_COUNTS 100000       // 200192 i
#define OFF_BSUM   300192       // 1024 i
#define OFF_ROWP   301216       // 100001 i (+3 pad)
#define OFF_BINNED 401220       // 3200000 u32 (src | dst_local<<17)
#define OFF_SORTED 3601220      // 3200000 u32 (src, grouped per dst node)
#define OFF_M1S    6801220      // 1600000 ushort bf16 (m1*dinv), 32 B/row
#define OFF_M2S    7601220      // 800000 ushort bf16 (m2*dinv), 16 B/row (pad 8th)
// total 8,001,220 dwords = 32.0 MB

// ------------------------------------------------------------- bf16 helpers
__device__ inline unsigned short f2bf(float f) {
    unsigned int u = __float_as_uint(f);
    return (unsigned short)((u + 0x7FFF + ((u >> 16) & 1)) >> 16);
}
__device__ inline float bf2f(unsigned short h) {
    return __uint_as_float((unsigned int)h << 16);
}

// ------------------------------------------------------------- pass 1: hist
__global__ void hist(const int* __restrict__ dst, int* __restrict__ counts) {
    __shared__ int cnt[NBKT];
    int t = threadIdx.x, b = blockIdx.x;
    for (int i = t; i < NBKT; i += 256) cnt[i] = 0;
    __syncthreads();
    int e0 = b * EDGES_PER_BLK;
    for (int e = e0 + t; e < e0 + EDGES_PER_BLK; e += 256)
        atomicAdd(&cnt[dst[e] >> BKT_SHIFT], 1);
    __syncthreads();
    for (int i = t; i < NBKT; i += 256)
        counts[i * NBLK_BIN + b] = cnt[i];
}

// ------------------------------------------------------------- scan chain
__global__ void scanA(int* __restrict__ counts, int* __restrict__ bsum) {
    __shared__ int s[256];
    int t = threadIdx.x;
    int i = blockIdx.x * 256 + t;
    int v = counts[i];
    s[t] = v;
    __syncthreads();
    for (int off = 1; off < 256; off <<= 1) {
        int a = (t >= off) ? s[t - off] : 0;
        __syncthreads();
        s[t] += a;
        __syncthreads();
    }
    counts[i] = s[t] - v;
    if (t == 255) bsum[blockIdx.x] = s[255];
}

__global__ void scanB(int* __restrict__ bsum) {
    __shared__ int s[1024];
    int t = threadIdx.x;
    int v = (t < NBLK_SCANA) ? bsum[t] : 0;
    s[t] = v;
    __syncthreads();
    for (int off = 1; off < 1024; off <<= 1) {
        int a = (t >= off) ? s[t - off] : 0;
        __syncthreads();
        s[t] += a;
        __syncthreads();
    }
    if (t < NBLK_SCANA) bsum[t] = s[t] - v;
}

__global__ void scanC(int* __restrict__ counts, const int* __restrict__ bsum) {
    int i = blockIdx.x * 256 + threadIdx.x;
    counts[i] += bsum[i >> 8];
}

// ------------------------------------------------------------- pass 2: bin
__global__ void binpass(const int* __restrict__ src, const int* __restrict__ dst,
                        const int* __restrict__ counts, unsigned int* __restrict__ binned) {
    __shared__ int cur[NBKT];
    int t = threadIdx.x, b = blockIdx.x;
    for (int i = t; i < NBKT; i += 256) cur[i] = counts[i * NBLK_BIN + b];
    __syncthreads();
    int e0 = b * EDGES_PER_BLK;
    for (int e = e0 + t; e < e0 + EDGES_PER_BLK; e += 256) {
        int d = dst[e];
        int pos = atomicAdd(&cur[d >> BKT_SHIFT], 1);
        binned[pos] = (unsigned int)src[e] | ((unsigned int)(d & (BKT_SIZE - 1)) << 17);
    }
}

// ---------------------- pass 3: per-bucket sort by node + rowptr + dinv
__global__ __launch_bounds__(512) void sortpass(const unsigned int* __restrict__ binned,
        const int* __restrict__ counts, unsigned int* __restrict__ sorted,
        int* __restrict__ rowptr, float* __restrict__ dinv) {
    __shared__ int cnt[BKT_SIZE];
    __shared__ int sc[BKT_SIZE];
    __shared__ int cur[BKT_SIZE];
    __shared__ unsigned int sbuf[SBUF_CAP];
    int t = threadIdx.x, b = blockIdx.x;
    int beg = counts[b * NBLK_BIN];
    int end = (b < NBKT - 1) ? counts[(b + 1) * NBLK_BIN] : N_EDGES;
    if (t < BKT_SIZE) cnt[t] = 0;
    __syncthreads();
    for (int e = beg + t; e < end; e += 512)
        atomicAdd(&cnt[(binned[e] >> 17) & (BKT_SIZE - 1)], 1);
    __syncthreads();
    int v = (t < BKT_SIZE) ? cnt[t] : 0;
    if (t < BKT_SIZE) sc[t] = v;
    __syncthreads();
    for (int off = 1; off < BKT_SIZE; off <<= 1) {
        int a = (t < BKT_SIZE && t >= off) ? sc[t - off] : 0;
        __syncthreads();
        if (t < BKT_SIZE) sc[t] += a;
        __syncthreads();
    }
    if (t < BKT_SIZE) {
        cur[t] = sc[t] - v;                    // exclusive, bucket-local
        int g = b * BKT_SIZE + t;
        if (g < N_NODES) {
            rowptr[g] = beg + sc[t] - v;
            dinv[g] = rsqrtf((float)v + 1.0f);  // +1 self loop
        }
    }
    if (b == 0 && t == 0) rowptr[N_NODES] = N_EDGES;
    __syncthreads();
    for (int e = beg + t; e < end; e += 512) {
        unsigned int u = binned[e];
        int pos = atomicAdd(&cur[(u >> 17) & (BKT_SIZE - 1)], 1);
        if (pos < SBUF_CAP) sbuf[pos] = u & 0x1FFFF;
    }
    __syncthreads();
    int n = end - beg;
    for (int i = t; i < n; i += 512) sorted[beg + i] = sbuf[i];
}

// ------------------------------------------- m1s = bf16((x @ W1) * dinv)
// Round-0 structure (coalesced row reads + butterfly combine), grid scaled
// 4x: 2084 blocks x 48 rows -> 8336 waves (~full occupancy) so the serial
// shuffle chains are hidden by TLP instead of restructuring.
#define G1_BLOCKS 2084
#define G1_ROWS_PER_BLOCK 48   // 2084*48 = 100032 >= 100000

__global__ __launch_bounds__(256) void gemm1(const float* __restrict__ x,
                                             const float* __restrict__ W1,
                                             const float* __restrict__ dinv,
                                             unsigned short* __restrict__ m1s) {
    __shared__ float P[16 * 32];
    const int t = threadIdx.x;
    const int lane = t & 63;
    const int w = t >> 6;
    const int half = w & 1;
    const int pair = w >> 1;
    const int c = half * 64 + lane;

    float4 wr[4][4];
#pragma unroll
    for (int r = 0; r < 4; ++r)
#pragma unroll
        for (int q = 0; q < 4; ++q)
            wr[r][q] = (c < NF4) ? *(const float4*)&W1[(4 * c + r) * 16 + 4 * q]
                                 : make_float4(0.f, 0.f, 0.f, 0.f);
    const int f = ((lane & 1) << 3) | ((lane & 2) << 1) | ((lane & 4) >> 1) | ((lane & 8) >> 3);

    const float4* x4 = (const float4*)x;
    int row0 = blockIdx.x * G1_ROWS_PER_BLOCK;
    int rowend = row0 + G1_ROWS_PER_BLOCK;
    if (rowend > N_NODES) rowend = N_NODES;

    for (int base = row0; base < rowend; base += 16) {
        for (int rr = 0; rr < 8; ++rr) {
            int row = base + pair * 8 + rr;
            float4 xv = make_float4(0.f, 0.f, 0.f, 0.f);
            if (row < rowend && c < NF4) xv = x4[(size_t)row * NF4 + c];
            float a[16];
#pragma unroll
            for (int q = 0; q < 4; ++q) {
                a[4*q+0] = xv.x*wr[0][q].x + xv.y*wr[1][q].x + xv.z*wr[2][q].x + xv.w*wr[3][q].x;
                a[4*q+1] = xv.x*wr[0][q].y + xv.y*wr[1][q].y + xv.z*wr[2][q].y + xv.w*wr[3][q].y;
                a[4*q+2] = xv.x*wr[0][q].z + xv.y*wr[1][q].z + xv.z*wr[2][q].z + xv.w*wr[3][q].z;
                a[4*q+3] = xv.x*wr[0][q].w + xv.y*wr[1][q].w + xv.z*wr[2][q].w + xv.w*wr[3][q].w;
            }
            bool hb = (lane & 1) != 0;
#pragma unroll
            for (int i = 0; i < 8; ++i) {
                float give = hb ? a[i] : a[i + 8];
                float got = __shfl_xor(give, 1, 64);
                a[i] = (hb ? a[i + 8] : a[i]) + got;
            }
            hb = (lane & 2) != 0;
#pragma unroll
            for (int i = 0; i < 4; ++i) {
                float give = hb ? a[i] : a[i + 4];
                float got = __shfl_xor(give, 2, 64);
                a[i] = (hb ? a[i + 4] : a[i]) + got;
            }
            hb = (lane & 4) != 0;
#pragma unroll
            for (int i = 0; i < 2; ++i) {
                float give = hb ? a[i] : a[i + 2];
                float got = __shfl_xor(give, 4, 64);
                a[i] = (hb ? a[i + 2] : a[i]) + got;
            }
            {
                hb = (lane & 8) != 0;
                float give = hb ? a[0] : a[1];
                float got = __shfl_xor(give, 8, 64);
                a[0] = (hb ? a[1] : a[0]) + got;
            }
            a[0] += __shfl_xor(a[0], 16, 64);
            a[0] += __shfl_xor(a[0], 32, 64);
            if (lane < 16) P[(pair * 8 + rr) * 32 + half * 16 + f] = a[0];
        }
        __syncthreads();
        {
            int rloc = t >> 4, j = t & 15;
            int row = base + rloc;
            if (row < rowend) {
                float val = P[rloc * 32 + j] + P[rloc * 32 + 16 + j];
                m1s[(size_t)row * 16 + j] = f2bf(val * dinv[row]);
            }
        }
        __syncthreads();
    }
}

// -------- layer-1 aggregate (register owner-computes) + bias + ReLU + h@W2
// 4 lanes per node; lane q owns features 4q..4q+3; per edge one uint2 (8B);
// the 4 lanes' loads form one 32B row segment. NO atomics.
__global__ __launch_bounds__(512) void agg1(const unsigned int* __restrict__ sorted,
        const int* __restrict__ rowptr, const float* __restrict__ dinv,
        const unsigned short* __restrict__ m1s, const float* __restrict__ b1,
        const float* __restrict__ W2, unsigned short* __restrict__ m2s) {
    __shared__ float acc[BKT_SIZE * 17];
    __shared__ float sW2[N_HID * N_CLS];
    __shared__ float sb1[N_HID];
    int t = threadIdx.x, b = blockIdx.x;
    if (t < N_HID * N_CLS) sW2[t] = W2[t];
    if (t < N_HID) sb1[t] = b1[t];
    int n = t >> 2, q = t & 3;
    int g = b * BKT_SIZE + n;
    float a0 = 0.f, a1 = 0.f, a2 = 0.f, a3 = 0.f;
    if (g < N_NODES) {
        int beg = rowptr[g], end = rowptr[g + 1];
        int p = beg;
        for (; p + 1 < end; p += 2) {
            unsigned int s0 = sorted[p], s1 = sorted[p + 1];
            uint2 w0 = *(const uint2*)&m1s[(size_t)s0 * 16 + q * 4];
            uint2 w1 = *(const uint2*)&m1s[(size_t)s1 * 16 + q * 4];
            a0 += __uint_as_float(w0.x << 16);
            a1 += __uint_as_float(w0.x & 0xFFFF0000u);
            a2 += __uint_as_float(w0.y << 16);
            a3 += __uint_as_float(w0.y & 0xFFFF0000u);
            a0 += __uint_as_float(w1.x << 16);
            a1 += __uint_as_float(w1.x & 0xFFFF0000u);
            a2 += __uint_as_float(w1.y << 16);
            a3 += __uint_as_float(w1.y & 0xFFFF0000u);
        }
        if (p < end) {
            unsigned int s0 = sorted[p];
            uint2 w0 = *(const uint2*)&m1s[(size_t)s0 * 16 + q * 4];
            a0 += __uint_as_float(w0.x << 16);
            a1 += __uint_as_float(w0.x & 0xFFFF0000u);
            a2 += __uint_as_float(w0.y << 16);
            a3 += __uint_as_float(w0.y & 0xFFFF0000u);
        }
    }
    float* ap = &acc[n * 17 + q * 4];
    ap[0] = a0; ap[1] = a1; ap[2] = a2; ap[3] = a3;
    __syncthreads();
    // h = relu(dinv_g * (acc + m1s_g) + b1), in place (stride 17)
    for (int idx = t; idx < BKT_SIZE * 16; idx += 512) {
        int nn = idx >> 4, jj = idx & 15;
        int gg = b * BKT_SIZE + nn;
        if (gg < N_NODES) {
            float di = dinv[gg];
            float hv = di * (acc[nn * 17 + jj] + bf2f(m1s[(size_t)gg * 16 + jj])) + sb1[jj];
            acc[nn * 17 + jj] = hv > 0.f ? hv : 0.f;
        }
    }
    __syncthreads();
    // m2s = bf16(dinv_g * (h @ W2)), stride 8, slot 7 = 0 pad
    for (int idx = t; idx < BKT_SIZE * 8; idx += 512) {
        int nn = idx >> 3, cc = idx & 7;
        int gg = b * BKT_SIZE + nn;
        if (gg < N_NODES) {
            float sum = 0.f;
            if (cc < N_CLS) {
#pragma unroll
                for (int jj = 0; jj < N_HID; ++jj) sum += acc[nn * 17 + jj] * sW2[jj * 7 + cc];
                sum *= dinv[gg];
            }
            m2s[(size_t)gg * 8 + cc] = f2bf(sum);
        }
    }
}

// -------- layer-2 aggregate (register owner-computes) + bias + log-softmax
// 2 lanes per node; lane q owns slots 4q..4q+3 (slot 7 = pad). NO atomics.
__global__ __launch_bounds__(256) void agg2(const unsigned int* __restrict__ sorted,
        const int* __restrict__ rowptr, const float* __restrict__ dinv,
        const unsigned short* __restrict__ m2s, const float* __restrict__ b2,
        float* __restrict__ out) {
    __shared__ float acc[BKT_SIZE * 9];
    int t = threadIdx.x, b = blockIdx.x;
    int n = t >> 1, q = t & 1;
    int g = b * BKT_SIZE + n;
    float a0 = 0.f, a1 = 0.f, a2 = 0.f, a3 = 0.f;
    if (g < N_NODES) {
        int beg = rowptr[g], end = rowptr[g + 1];
        int p = beg;
        for (; p + 1 < end; p += 2) {
            unsigned int s0 = sorted[p], s1 = sorted[p + 1];
            uint2 w0 = *(const uint2*)&m2s[(size_t)s0 * 8 + q * 4];
            uint2 w1 = *(const uint2*)&m2s[(size_t)s1 * 8 + q * 4];
            a0 += __uint_as_float(w0.x << 16);
            a1 += __uint_as_float(w0.x & 0xFFFF0000u);
            a2 += __uint_as_float(w0.y << 16);
            a3 += __uint_as_float(w0.y & 0xFFFF0000u);
            a0 += __uint_as_float(w1.x << 16);
            a1 += __uint_as_float(w1.x & 0xFFFF0000u);
            a2 += __uint_as_float(w1.y << 16);
            a3 += __uint_as_float(w1.y & 0xFFFF0000u);
        }
        if (p < end) {
            unsigned int s0 = sorted[p];
            uint2 w0 = *(const uint2*)&m2s[(size_t)s0 * 8 + q * 4];
            a0 += __uint_as_float(w0.x << 16);
            a1 += __uint_as_float(w0.x & 0xFFFF0000u);
            a2 += __uint_as_float(w0.y << 16);
            a3 += __uint_as_float(w0.y & 0xFFFF0000u);
        }
    }
    float* ap = &acc[n * 9 + q * 4];
    ap[0] = a0; ap[1] = a1; ap[2] = a2; ap[3] = a3;
    __syncthreads();
    int j = t & 7;
    for (int pass = 0; pass < 4; ++pass) {
        int nn = (t >> 3) + pass * 32;
        int gg = b * BKT_SIZE + nn;
        bool valid = (gg < N_NODES) && (j < N_CLS);
        float v = -1e30f;
        if (valid) {
            float di = dinv[gg];
            v = di * (acc[nn * 9 + j] + bf2f(m2s[(size_t)gg * 8 + j])) + b2[j];
        }
        float mx = v;
#pragma unroll
        for (int off = 1; off < 8; off <<= 1) mx = fmaxf(mx, __shfl_xor(mx, off, 8));
        float ex = valid ? expf(v - mx) : 0.f;
        float sum = ex;
#pragma unroll
        for (int off = 1; off < 8; off <<= 1) sum += __shfl_xor(sum, off, 8);
        float ls = mx + logf(sum);
        if (valid) out[(size_t)gg * 7 + j] = v - ls;
    }
}

// ----------------------------------------------------------------
extern "C" void kernel_launch(void* const* d_in, const int* in_sizes, int n_in,
                              void* d_out, int out_size, void* d_ws, size_t ws_size,
                              hipStream_t stream) {
    const float* x  = (const float*)d_in[0];
    const int*   ei = (const int*)d_in[1];
    const float* W1 = (const float*)d_in[2];
    const float* b1 = (const float*)d_in[3];
    const float* W2 = (const float*)d_in[4];
    const float* b2 = (const float*)d_in[5];
    float* out = (float*)d_out;
    char*  wsb = (char*)d_ws;   // needs 32.0 MB

    const int* src = ei;               // edge_index[0]
    const int* dst = ei + N_EDGES;     // edge_index[1]

    float*          dinv   = (float*)wsb + OFF_DINV;
    int*            counts = (int*)wsb + OFF_COUNTS;
    int*            bsum   = (int*)wsb + OFF_BSUM;
    int*            rowptr = (int*)wsb + OFF_ROWP;
    unsigned int*   binned = (unsigned int*)wsb + OFF_BINNED;
    unsigned int*   sorted = (unsigned int*)wsb + OFF_SORTED;
    unsigned short* m1s    = (unsigned short*)(wsb + (size_t)OFF_M1S * 4);
    unsigned short* m2s    = (unsigned short*)(wsb + (size_t)OFF_M2S * 4);

    hist     <<<NBLK_BIN, 256, 0, stream>>>(dst, counts);
    scanA    <<<NBLK_SCANA, 256, 0, stream>>>(counts, bsum);
    scanB    <<<1, 1024, 0, stream>>>(bsum);
    scanC    <<<NBLK_SCANA, 256, 0, stream>>>(counts, bsum);
    binpass  <<<NBLK_BIN, 256, 0, stream>>>(src, dst, counts, binned);
    sortpass <<<NBKT, 512, 0, stream>>>(binned, counts, sorted, rowptr, dinv);
    gemm1    <<<G1_BLOCKS, 256, 0, stream>>>(x, W1, dinv, m1s);
    agg1     <<<NBKT, 512, 0, stream>>>(sorted, rowptr, dinv, m1s, b1, W2, m2s);
    agg2     <<<NBKT, 256, 0, stream>>>(sorted, rowptr, dinv, m2s, b2, out);
}

// Round 3
// 506.211 us; speedup vs baseline: 1.2812x; 1.0285x over previous
//
#include <hip/hip_runtime.h>
#include <math.h>

#define N_NODES 100000
#define N_EDGES 3200000
#define N_FEAT  500
#define NF4     125      // N_FEAT / 4
#define N_HID   16
#define N_CLS   7

#define BKT_SHIFT 7
#define BKT_SIZE  128
#define NBKT      782            // ceil(100000/128)
#define NBLK_BIN  256            // edge-chunk blocks for hist/binpass
#define EDGES_PER_BLK 12500      // 256 * 12500 = 3.2M exactly
#define COUNTS_LEN (NBKT * NBLK_BIN)   // 200192
#define NBLK_SCANA (COUNTS_LEN / 256)  // 782 exactly
#define SBUF_CAP  5632           // max edges/bucket (mean 4092, sd 64 -> 24 sd)

// ---------------- workspace layout (dword offsets) --------------------------
#define OFF_DINV   0            // 100000 f
#define OFF_COUNTS 100000       // 200192 i
#define OFF_BSUM   300192       // 1024 i
#define OFF_ROWP   301216       // 100001 i (+3 pad)
#define OFF_BINNED 401220       // 3200000 u32; dead after sortpass -> reused for packed W1
#define OFF_SORTED 3601220      // 3200000 u32 (src, grouped per dst node)
#define OFF_M1S    6801220      // 1600000 ushort bf16 (m1*dinv), 32 B/row
#define OFF_M2S    7601220      // 800000 ushort bf16 (m2*dinv), 16 B/row (pad 8th)
// total 8,001,220 dwords = 32.0 MB

typedef __attribute__((ext_vector_type(8))) short short8v;
typedef __attribute__((ext_vector_type(4))) float f32x4v;

// ------------------------------------------------------------- bf16 helpers
__device__ inline unsigned short f2bf(float f) {
    unsigned int u = __float_as_uint(f);
    return (unsigned short)((u + 0x7FFF + ((u >> 16) & 1)) >> 16);
}
__device__ inline float bf2f(unsigned short h) {
    return __uint_as_float((unsigned int)h << 16);
}

// ------------------------------------------------------------- pass 1: hist
__global__ void hist(const int* __restrict__ dst, int* __restrict__ counts) {
    __shared__ int cnt[NBKT];
    int t = threadIdx.x, b = blockIdx.x;
    for (int i = t; i < NBKT; i += 256) cnt[i] = 0;
    __syncthreads();
    int e0 = b * EDGES_PER_BLK;
    for (int e = e0 + t; e < e0 + EDGES_PER_BLK; e += 256)
        atomicAdd(&cnt[dst[e] >> BKT_SHIFT], 1);
    __syncthreads();
    for (int i = t; i < NBKT; i += 256)
        counts[i * NBLK_BIN + b] = cnt[i];
}

// ------------------------------------------------------------- scan chain
__global__ void scanA(int* __restrict__ counts, int* __restrict__ bsum) {
    __shared__ int s[256];
    int t = threadIdx.x;
    int i = blockIdx.x * 256 + t;
    int v = counts[i];
    s[t] = v;
    __syncthreads();
    for (int off = 1; off < 256; off <<= 1) {
        int a = (t >= off) ? s[t - off] : 0;
        __syncthreads();
        s[t] += a;
        __syncthreads();
    }
    counts[i] = s[t] - v;
    if (t == 255) bsum[blockIdx.x] = s[255];
}

__global__ void scanB(int* __restrict__ bsum) {
    __shared__ int s[1024];
    int t = threadIdx.x;
    int v = (t < NBLK_SCANA) ? bsum[t] : 0;
    s[t] = v;
    __syncthreads();
    for (int off = 1; off < 1024; off <<= 1) {
        int a = (t >= off) ? s[t - off] : 0;
        __syncthreads();
        s[t] += a;
        __syncthreads();
    }
    if (t < NBLK_SCANA) bsum[t] = s[t] - v;
}

// ---- scanC folded into binpass/sortpass: global prefix = counts[j] + bsum[j>>8]

// ------------------------------------------------------------- pass 2: bin
__global__ void binpass(const int* __restrict__ src, const int* __restrict__ dst,
                        const int* __restrict__ counts, const int* __restrict__ bsum,
                        unsigned int* __restrict__ binned) {
    __shared__ int cur[NBKT];
    int t = threadIdx.x, b = blockIdx.x;
    for (int i = t; i < NBKT; i += 256) cur[i] = counts[i * NBLK_BIN + b] + bsum[i];
    __syncthreads();
    int e0 = b * EDGES_PER_BLK;
    for (int e = e0 + t; e < e0 + EDGES_PER_BLK; e += 256) {
        int d = dst[e];
        int pos = atomicAdd(&cur[d >> BKT_SHIFT], 1);
        binned[pos] = (unsigned int)src[e] | ((unsigned int)(d & (BKT_SIZE - 1)) << 17);
    }
}

// ---------------------- pass 3: per-bucket sort by node + rowptr + dinv
__global__ __launch_bounds__(512) void sortpass(const unsigned int* __restrict__ binned,
        const int* __restrict__ counts, const int* __restrict__ bsum,
        unsigned int* __restrict__ sorted,
        int* __restrict__ rowptr, float* __restrict__ dinv) {
    __shared__ int cnt[BKT_SIZE];
    __shared__ int sc[BKT_SIZE];
    __shared__ int cur[BKT_SIZE];
    __shared__ unsigned int sbuf[SBUF_CAP];
    int t = threadIdx.x, b = blockIdx.x;
    int beg = counts[b * NBLK_BIN] + bsum[b];
    int end = (b < NBKT - 1) ? counts[(b + 1) * NBLK_BIN] + bsum[b + 1] : N_EDGES;
    if (t < BKT_SIZE) cnt[t] = 0;
    __syncthreads();
    for (int e = beg + t; e < end; e += 512)
        atomicAdd(&cnt[(binned[e] >> 17) & (BKT_SIZE - 1)], 1);
    __syncthreads();
    int v = (t < BKT_SIZE) ? cnt[t] : 0;
    if (t < BKT_SIZE) sc[t] = v;
    __syncthreads();
    for (int off = 1; off < BKT_SIZE; off <<= 1) {
        int a = (t < BKT_SIZE && t >= off) ? sc[t - off] : 0;
        __syncthreads();
        if (t < BKT_SIZE) sc[t] += a;
        __syncthreads();
    }
    if (t < BKT_SIZE) {
        cur[t] = sc[t] - v;                    // exclusive, bucket-local
        int g = b * BKT_SIZE + t;
        if (g < N_NODES) {
            rowptr[g] = beg + sc[t] - v;
            dinv[g] = rsqrtf((float)v + 1.0f);  // +1 self loop
        }
    }
    if (b == 0 && t == 0) rowptr[N_NODES] = N_EDGES;
    __syncthreads();
    for (int e = beg + t; e < end; e += 512) {
        unsigned int u = binned[e];
        int pos = atomicAdd(&cur[(u >> 17) & (BKT_SIZE - 1)], 1);
        if (pos < SBUF_CAP) sbuf[pos] = u & 0x1FFFF;
    }
    __syncthreads();
    int n = end - beg;
    for (int i = t; i < n; i += 512) sorted[beg + i] = sbuf[i];
}

// ------------------------------------------- W1 fragment pre-pack (hi/lo bf16)
// Layout: wp[s*64 + lane] = B_hi frag for K-step s (k = s*32 + (lane>>4)*8 + e,
// col = lane&15, e=0..7 packed 2/dword); wp[1024 + ...] = B_lo. k>=500 -> 0.
__global__ void wpack(const float* __restrict__ W1, uint4* __restrict__ wp) {
    int p = blockIdx.x * 256 + threadIdx.x;
    if (p >= 1024) return;
    int s = p >> 6, l = p & 63;
    int col = l & 15, kb = s * 32 + (l >> 4) * 8;
    unsigned int hw[4], lw[4];
#pragma unroll
    for (int d = 0; d < 4; ++d) {
        unsigned int hpair = 0, lpair = 0;
#pragma unroll
        for (int e = 0; e < 2; ++e) {
            int k = kb + d * 2 + e;
            float w0 = (k < N_FEAT) ? W1[k * 16 + col] : 0.f;
            unsigned int u = __float_as_uint(w0);
            unsigned int uh = u & 0xFFFF0000u;        // hi = truncated bf16
            float res = w0 - __uint_as_float(uh);     // exact residual
            hpair |= (uh >> 16) << (16 * e);
            lpair |= (unsigned int)f2bf(res) << (16 * e);
        }
        hw[d] = hpair; lw[d] = lpair;
    }
    wp[p] = make_uint4(hw[0], hw[1], hw[2], hw[3]);
    wp[1024 + p] = make_uint4(lw[0], lw[1], lw[2], lw[3]);
}

// ------------------------------------------- m1s = bf16((x @ W1) * dinv)
// MFMA rewrite: v_mfma_f32_16x16x32_bf16, 3-term hi/lo split => fp32-accurate.
// 782 blocks x 4 waves; wave owns 32 rows (2 row-tiles); K padded 500->512
// (B frags zero there). No LDS, no syncthreads, no shuffle chains.
#define G1_NBLK 782

__device__ inline void split8(const float4 a, const float4 b, short8v& hi, short8v& lo) {
    float f[8] = {a.x, a.y, a.z, a.w, b.x, b.y, b.z, b.w};
#pragma unroll
    for (int i = 0; i < 8; ++i) {
        unsigned int u = __float_as_uint(f[i]);
        unsigned int uh = u & 0xFFFF0000u;
        hi[i] = (short)(u >> 16);
        lo[i] = (short)f2bf(f[i] - __uint_as_float(uh));
    }
}

__global__ __launch_bounds__(256) void gemm1(const float* __restrict__ x,
        const uint4* __restrict__ wp, const float* __restrict__ dinv,
        unsigned short* __restrict__ m1s) {
    const int t = threadIdx.x, b = blockIdx.x;
    const int lane = t & 63, w = t >> 6;
    const int g = lane >> 4;
    const int rowbase = b * 128 + w * 32;
    const int r0 = rowbase + (lane & 15);
    const int r1 = r0 + 16;
    const float* pA0 = x + (size_t)(r0 < N_NODES ? r0 : N_NODES - 1) * N_FEAT + g * 8;
    const float* pA1 = x + (size_t)(r1 < N_NODES ? r1 : N_NODES - 1) * N_FEAT + g * 8;
    f32x4v acc0 = {0.f, 0.f, 0.f, 0.f};
    f32x4v acc1 = {0.f, 0.f, 0.f, 0.f};
#pragma unroll
    for (int s = 0; s < 16; ++s) {
        short8v bh = *reinterpret_cast<const short8v*>(&wp[s * 64 + lane]);
        short8v bl = *reinterpret_cast<const short8v*>(&wp[1024 + s * 64 + lane]);
        float4 a0, a1, c0, c1;
        if (s < 15) {
            a0 = *(const float4*)(pA0 + s * 32);
            a1 = *(const float4*)(pA0 + s * 32 + 4);
            c0 = *(const float4*)(pA1 + s * 32);
            c1 = *(const float4*)(pA1 + s * 32 + 4);
        } else {               // K tail: k = 480 + g*8 + e, valid only k < 500
            const float4 z = make_float4(0.f, 0.f, 0.f, 0.f);
            a0 = (g <= 2) ? *(const float4*)(pA0 + 480) : z;
            a1 = (g <= 1) ? *(const float4*)(pA0 + 484) : z;
            c0 = (g <= 2) ? *(const float4*)(pA1 + 480) : z;
            c1 = (g <= 1) ? *(const float4*)(pA1 + 484) : z;
        }
        short8v ah, al, ch, cl;
        split8(a0, a1, ah, al);
        split8(c0, c1, ch, cl);
        acc0 = __builtin_amdgcn_mfma_f32_16x16x32_bf16(ah, bh, acc0, 0, 0, 0);
        acc1 = __builtin_amdgcn_mfma_f32_16x16x32_bf16(ch, bh, acc1, 0, 0, 0);
        acc0 = __builtin_amdgcn_mfma_f32_16x16x32_bf16(al, bh, acc0, 0, 0, 0);
        acc1 = __builtin_amdgcn_mfma_f32_16x16x32_bf16(cl, bh, acc1, 0, 0, 0);
        acc0 = __builtin_amdgcn_mfma_f32_16x16x32_bf16(ah, bl, acc0, 0, 0, 0);
        acc1 = __builtin_amdgcn_mfma_f32_16x16x32_bf16(ch, bl, acc1, 0, 0, 0);
    }
    // C/D layout: col = lane&15, row = (lane>>4)*4 + j
    const int col = lane & 15;
#pragma unroll
    for (int j = 0; j < 4; ++j) {
        int r = rowbase + g * 4 + j;
        if (r < N_NODES) m1s[(size_t)r * 16 + col] = f2bf(acc0[j] * dinv[r]);
        int r2 = r + 16;
        if (r2 < N_NODES) m1s[(size_t)r2 * 16 + col] = f2bf(acc1[j] * dinv[r2]);
    }
}

// -------- layer-1 aggregate (register owner-computes) + bias + ReLU + h@W2
// 4 lanes per node; lane q owns features 4q..4q+3; per edge one uint2 (8B);
// the 4 lanes' loads form one 32B row segment. NO atomics.
__global__ __launch_bounds__(512) void agg1(const unsigned int* __restrict__ sorted,
        const int* __restrict__ rowptr, const float* __restrict__ dinv,
        const unsigned short* __restrict__ m1s, const float* __restrict__ b1,
        const float* __restrict__ W2, unsigned short* __restrict__ m2s) {
    __shared__ float acc[BKT_SIZE * 17];
    __shared__ float sW2[N_HID * N_CLS];
    __shared__ float sb1[N_HID];
    int t = threadIdx.x, b = blockIdx.x;
    if (t < N_HID * N_CLS) sW2[t] = W2[t];
    if (t < N_HID) sb1[t] = b1[t];
    int n = t >> 2, q = t & 3;
    int g = b * BKT_SIZE + n;
    float a0 = 0.f, a1 = 0.f, a2 = 0.f, a3 = 0.f;
    if (g < N_NODES) {
        int beg = rowptr[g], end = rowptr[g + 1];
        int p = beg;
        for (; p + 1 < end; p += 2) {
            unsigned int s0 = sorted[p], s1 = sorted[p + 1];
            uint2 w0 = *(const uint2*)&m1s[(size_t)s0 * 16 + q * 4];
            uint2 w1 = *(const uint2*)&m1s[(size_t)s1 * 16 + q * 4];
            a0 += __uint_as_float(w0.x << 16);
            a1 += __uint_as_float(w0.x & 0xFFFF0000u);
            a2 += __uint_as_float(w0.y << 16);
            a3 += __uint_as_float(w0.y & 0xFFFF0000u);
            a0 += __uint_as_float(w1.x << 16);
            a1 += __uint_as_float(w1.x & 0xFFFF0000u);
            a2 += __uint_as_float(w1.y << 16);
            a3 += __uint_as_float(w1.y & 0xFFFF0000u);
        }
        if (p < end) {
            unsigned int s0 = sorted[p];
            uint2 w0 = *(const uint2*)&m1s[(size_t)s0 * 16 + q * 4];
            a0 += __uint_as_float(w0.x << 16);
            a1 += __uint_as_float(w0.x & 0xFFFF0000u);
            a2 += __uint_as_float(w0.y << 16);
            a3 += __uint_as_float(w0.y & 0xFFFF0000u);
        }
    }
    float* ap = &acc[n * 17 + q * 4];
    ap[0] = a0; ap[1] = a1; ap[2] = a2; ap[3] = a3;
    __syncthreads();
    // h = relu(dinv_g * (acc + m1s_g) + b1), in place (stride 17)
    for (int idx = t; idx < BKT_SIZE * 16; idx += 512) {
        int nn = idx >> 4, jj = idx & 15;
        int gg = b * BKT_SIZE + nn;
        if (gg < N_NODES) {
            float di = dinv[gg];
            float hv = di * (acc[nn * 17 + jj] + bf2f(m1s[(size_t)gg * 16 + jj])) + sb1[jj];
            acc[nn * 17 + jj] = hv > 0.f ? hv : 0.f;
        }
    }
    __syncthreads();
    // m2s = bf16(dinv_g * (h @ W2)), stride 8, slot 7 = 0 pad
    for (int idx = t; idx < BKT_SIZE * 8; idx += 512) {
        int nn = idx >> 3, cc = idx & 7;
        int gg = b * BKT_SIZE + nn;
        if (gg < N_NODES) {
            float sum = 0.f;
            if (cc < N_CLS) {
#pragma unroll
                for (int jj = 0; jj < N_HID; ++jj) sum += acc[nn * 17 + jj] * sW2[jj * 7 + cc];
                sum *= dinv[gg];
            }
            m2s[(size_t)gg * 8 + cc] = f2bf(sum);
        }
    }
}

// -------- layer-2 aggregate (register owner-computes) + bias + log-softmax
// 2 lanes per node; lane q owns slots 4q..4q+3 (slot 7 = pad). NO atomics.
__global__ __launch_bounds__(256) void agg2(const unsigned int* __restrict__ sorted,
        const int* __restrict__ rowptr, const float* __restrict__ dinv,
        const unsigned short* __restrict__ m2s, const float* __restrict__ b2,
        float* __restrict__ out) {
    __shared__ float acc[BKT_SIZE * 9];
    int t = threadIdx.x, b = blockIdx.x;
    int n = t >> 1, q = t & 1;
    int g = b * BKT_SIZE + n;
    float a0 = 0.f, a1 = 0.f, a2 = 0.f, a3 = 0.f;
    if (g < N_NODES) {
        int beg = rowptr[g], end = rowptr[g + 1];
        int p = beg;
        for (; p + 1 < end; p += 2) {
            unsigned int s0 = sorted[p], s1 = sorted[p + 1];
            uint2 w0 = *(const uint2*)&m2s[(size_t)s0 * 8 + q * 4];
            uint2 w1 = *(const uint2*)&m2s[(size_t)s1 * 8 + q * 4];
            a0 += __uint_as_float(w0.x << 16);
            a1 += __uint_as_float(w0.x & 0xFFFF0000u);
            a2 += __uint_as_float(w0.y << 16);
            a3 += __uint_as_float(w0.y & 0xFFFF0000u);
            a0 += __uint_as_float(w1.x << 16);
            a1 += __uint_as_float(w1.x & 0xFFFF0000u);
            a2 += __uint_as_float(w1.y << 16);
            a3 += __uint_as_float(w1.y & 0xFFFF0000u);
        }
        if (p < end) {
            unsigned int s0 = sorted[p];
            uint2 w0 = *(const uint2*)&m2s[(size_t)s0 * 8 + q * 4];
            a0 += __uint_as_float(w0.x << 16);
            a1 += __uint_as_float(w0.x & 0xFFFF0000u);
            a2 += __uint_as_float(w0.y << 16);
            a3 += __uint_as_float(w0.y & 0xFFFF0000u);
        }
    }
    float* ap = &acc[n * 9 + q * 4];
    ap[0] = a0; ap[1] = a1; ap[2] = a2; ap[3] = a3;
    __syncthreads();
    int j = t & 7;
    for (int pass = 0; pass < 4; ++pass) {
        int nn = (t >> 3) + pass * 32;
        int gg = b * BKT_SIZE + nn;
        bool valid = (gg < N_NODES) && (j < N_CLS);
        float v = -1e30f;
        if (valid) {
            float di = dinv[gg];
            v = di * (acc[nn * 9 + j] + bf2f(m2s[(size_t)gg * 8 + j])) + b2[j];
        }
        float mx = v;
#pragma unroll
        for (int off = 1; off < 8; off <<= 1) mx = fmaxf(mx, __shfl_xor(mx, off, 8));
        float ex = valid ? expf(v - mx) : 0.f;
        float sum = ex;
#pragma unroll
        for (int off = 1; off < 8; off <<= 1) sum += __shfl_xor(sum, off, 8);
        float ls = mx + logf(sum);
        if (valid) out[(size_t)gg * 7 + j] = v - ls;
    }
}

// ----------------------------------------------------------------
extern "C" void kernel_launch(void* const* d_in, const int* in_sizes, int n_in,
                              void* d_out, int out_size, void* d_ws, size_t ws_size,
                              hipStream_t stream) {
    const float* x  = (const float*)d_in[0];
    const int*   ei = (const int*)d_in[1];
    const float* W1 = (const float*)d_in[2];
    const float* b1 = (const float*)d_in[3];
    const float* W2 = (const float*)d_in[4];
    const float* b2 = (const float*)d_in[5];
    float* out = (float*)d_out;
    char*  wsb = (char*)d_ws;   // needs 32.0 MB

    const int* src = ei;               // edge_index[0]
    const int* dst = ei + N_EDGES;     // edge_index[1]

    float*          dinv   = (float*)wsb + OFF_DINV;
    int*            counts = (int*)wsb + OFF_COUNTS;
    int*            bsum   = (int*)wsb + OFF_BSUM;
    int*            rowptr = (int*)wsb + OFF_ROWP;
    unsigned int*   binned = (unsigned int*)wsb + OFF_BINNED;
    unsigned int*   sorted = (unsigned int*)wsb + OFF_SORTED;
    unsigned short* m1s    = (unsigned short*)(wsb + (size_t)OFF_M1S * 4);
    unsigned short* m2s    = (unsigned short*)(wsb + (size_t)OFF_M2S * 4);
    uint4*          wp     = (uint4*)binned;   // binned is dead after sortpass

    hist     <<<NBLK_BIN, 256, 0, stream>>>(dst, counts);
    scanA    <<<NBLK_SCANA, 256, 0, stream>>>(counts, bsum);
    scanB    <<<1, 1024, 0, stream>>>(bsum);
    binpass  <<<NBLK_BIN, 256, 0, stream>>>(src, dst, counts, bsum, binned);
    sortpass <<<NBKT, 512, 0, stream>>>(binned, counts, bsum, sorted, rowptr, dinv);
    wpack    <<<4, 256, 0, stream>>>(W1, wp);
    gemm1    <<<G1_NBLK, 256, 0, stream>>>(x, wp, dinv, m1s);
    agg1     <<<NBKT, 512, 0, stream>>>(sorted, rowptr, dinv, m1s, b1, W2, m2s);
    agg2     <<<NBKT, 256, 0, stream>>>(sorted, rowptr, dinv, m2s, b2, out);
}

// Round 4
// 497.285 us; speedup vs baseline: 1.3042x; 1.0179x over previous
//
#include <hip/hip_runtime.h>
#include <math.h>

#define N_NODES 100000
#define N_EDGES 3200000
#define N_FEAT  500
#define NF4     125      // N_FEAT / 4
#define N_HID   16
#define N_CLS   7

#define BKT_SHIFT 7
#define BKT_SIZE  128
#define NBKT      782            // ceil(100000/128)
#define NBLK_BIN  256            // edge-chunk blocks for hist/binpass
#define EDGES_PER_BLK 12500      // 256 * 12500 = 3.2M exactly
#define COUNTS_LEN (NBKT * NBLK_BIN)   // 200192
#define NBLK_SCANA (COUNTS_LEN / 256)  // 782 exactly
#define SBUF_CAP  5632           // max edges/bucket (mean 4092, sd 64 -> 24 sd)

// ---------------- workspace layout (dword offsets) --------------------------
#define OFF_DINV   0            // 100000 f
#define OFF_COUNTS 100000       // 200192 i
#define OFF_BSUM   300192       // 1024 i
#define OFF_ROWP   301216       // 100001 i (+3 pad)
#define OFF_BINNED 401220       // 3200000 u32; dead after sortpass -> reused for packed W1
#define OFF_SORTED 3601220      // 3200000 u32 (src, grouped per dst node)
#define OFF_M1S    6801220      // 1600000 ushort bf16 (m1*dinv), 32 B/row
#define OFF_M2S    7601220      // 800000 ushort bf16 (m2*dinv), 16 B/row (pad 8th)
// total 8,001,220 dwords = 32.0 MB

typedef __attribute__((ext_vector_type(8))) short short8v;
typedef __attribute__((ext_vector_type(4))) float f32x4v;

// ------------------------------------------------------------- bf16 helpers
__device__ inline unsigned short f2bf(float f) {
    unsigned int u = __float_as_uint(f);
    return (unsigned short)((u + 0x7FFF + ((u >> 16) & 1)) >> 16);
}
__device__ inline float bf2f(unsigned short h) {
    return __uint_as_float((unsigned int)h << 16);
}

__device__ inline void gload16(const void* g, void* l) {
    __builtin_amdgcn_global_load_lds(
        (const __attribute__((address_space(1))) void*)g,
        (__attribute__((address_space(3))) void*)l, 16, 0, 0);
}

// ------------------------------------------------------------- pass 1: hist
__global__ void hist(const int* __restrict__ dst, int* __restrict__ counts) {
    __shared__ int cnt[NBKT];
    int t = threadIdx.x, b = blockIdx.x;
    for (int i = t; i < NBKT; i += 256) cnt[i] = 0;
    __syncthreads();
    int e0 = b * EDGES_PER_BLK;
    for (int e = e0 + t; e < e0 + EDGES_PER_BLK; e += 256)
        atomicAdd(&cnt[dst[e] >> BKT_SHIFT], 1);
    __syncthreads();
    for (int i = t; i < NBKT; i += 256)
        counts[i * NBLK_BIN + b] = cnt[i];
}

// ------------------------------------------------------------- scan chain
__global__ void scanA(int* __restrict__ counts, int* __restrict__ bsum) {
    __shared__ int s[256];
    int t = threadIdx.x;
    int i = blockIdx.x * 256 + t;
    int v = counts[i];
    s[t] = v;
    __syncthreads();
    for (int off = 1; off < 256; off <<= 1) {
        int a = (t >= off) ? s[t - off] : 0;
        __syncthreads();
        s[t] += a;
        __syncthreads();
    }
    counts[i] = s[t] - v;
    if (t == 255) bsum[blockIdx.x] = s[255];
}

__global__ void scanB(int* __restrict__ bsum) {
    __shared__ int s[1024];
    int t = threadIdx.x;
    int v = (t < NBLK_SCANA) ? bsum[t] : 0;
    s[t] = v;
    __syncthreads();
    for (int off = 1; off < 1024; off <<= 1) {
        int a = (t >= off) ? s[t - off] : 0;
        __syncthreads();
        s[t] += a;
        __syncthreads();
    }
    if (t < NBLK_SCANA) bsum[t] = s[t] - v;
}

// ---- scanC folded into binpass/sortpass: global prefix = counts[j] + bsum[j>>8]

// ------------------------------------------------------------- pass 2: bin
__global__ void binpass(const int* __restrict__ src, const int* __restrict__ dst,
                        const int* __restrict__ counts, const int* __restrict__ bsum,
                        unsigned int* __restrict__ binned) {
    __shared__ int cur[NBKT];
    int t = threadIdx.x, b = blockIdx.x;
    for (int i = t; i < NBKT; i += 256) cur[i] = counts[i * NBLK_BIN + b] + bsum[i];
    __syncthreads();
    int e0 = b * EDGES_PER_BLK;
    for (int e = e0 + t; e < e0 + EDGES_PER_BLK; e += 256) {
        int d = dst[e];
        int pos = atomicAdd(&cur[d >> BKT_SHIFT], 1);
        binned[pos] = (unsigned int)src[e] | ((unsigned int)(d & (BKT_SIZE - 1)) << 17);
    }
}

// ---------------------- pass 3: per-bucket sort by node + rowptr + dinv
__global__ __launch_bounds__(512) void sortpass(const unsigned int* __restrict__ binned,
        const int* __restrict__ counts, const int* __restrict__ bsum,
        unsigned int* __restrict__ sorted,
        int* __restrict__ rowptr, float* __restrict__ dinv) {
    __shared__ int cnt[BKT_SIZE];
    __shared__ int sc[BKT_SIZE];
    __shared__ int cur[BKT_SIZE];
    __shared__ unsigned int sbuf[SBUF_CAP];
    int t = threadIdx.x, b = blockIdx.x;
    int beg = counts[b * NBLK_BIN] + bsum[b];
    int end = (b < NBKT - 1) ? counts[(b + 1) * NBLK_BIN] + bsum[b + 1] : N_EDGES;
    if (t < BKT_SIZE) cnt[t] = 0;
    __syncthreads();
    for (int e = beg + t; e < end; e += 512)
        atomicAdd(&cnt[(binned[e] >> 17) & (BKT_SIZE - 1)], 1);
    __syncthreads();
    int v = (t < BKT_SIZE) ? cnt[t] : 0;
    if (t < BKT_SIZE) sc[t] = v;
    __syncthreads();
    for (int off = 1; off < BKT_SIZE; off <<= 1) {
        int a = (t < BKT_SIZE && t >= off) ? sc[t - off] : 0;
        __syncthreads();
        if (t < BKT_SIZE) sc[t] += a;
        __syncthreads();
    }
    if (t < BKT_SIZE) {
        cur[t] = sc[t] - v;                    // exclusive, bucket-local
        int g = b * BKT_SIZE + t;
        if (g < N_NODES) {
            rowptr[g] = beg + sc[t] - v;
            dinv[g] = rsqrtf((float)v + 1.0f);  // +1 self loop
        }
    }
    if (b == 0 && t == 0) rowptr[N_NODES] = N_EDGES;
    __syncthreads();
    for (int e = beg + t; e < end; e += 512) {
        unsigned int u = binned[e];
        int pos = atomicAdd(&cur[(u >> 17) & (BKT_SIZE - 1)], 1);
        if (pos < SBUF_CAP) sbuf[pos] = u & 0x1FFFF;
    }
    __syncthreads();
    int n = end - beg;
    for (int i = t; i < n; i += 512) sorted[beg + i] = sbuf[i];
}

// ------------------------------------------- W1 fragment pre-pack (hi/lo bf16)
// Layout: wp[s*64 + lane] = B_hi frag for K-step s (k = s*32 + (lane>>4)*8 + e,
// col = lane&15, e=0..7 packed 2/dword); wp[1024 + ...] = B_lo. k>=500 -> 0.
__global__ void wpack(const float* __restrict__ W1, uint4* __restrict__ wp) {
    int p = blockIdx.x * 256 + threadIdx.x;
    if (p >= 1024) return;
    int s = p >> 6, l = p & 63;
    int col = l & 15, kb = s * 32 + (l >> 4) * 8;
    unsigned int hw[4], lw[4];
#pragma unroll
    for (int d = 0; d < 4; ++d) {
        unsigned int hpair = 0, lpair = 0;
#pragma unroll
        for (int e = 0; e < 2; ++e) {
            int k = kb + d * 2 + e;
            float w0 = (k < N_FEAT) ? W1[k * 16 + col] : 0.f;
            unsigned int u = __float_as_uint(w0);
            unsigned int uh = u & 0xFFFF0000u;        // hi = truncated bf16
            float res = w0 - __uint_as_float(uh);     // exact residual
            hpair |= (uh >> 16) << (16 * e);
            lpair |= (unsigned int)f2bf(res) << (16 * e);
        }
        hw[d] = hpair; lw[d] = lpair;
    }
    wp[p] = make_uint4(hw[0], hw[1], hw[2], hw[3]);
    wp[1024 + p] = make_uint4(lw[0], lw[1], lw[2], lw[3]);
}

// ------------------------------------------- m1s = bf16((x @ W1) * dinv)
// Canonical LDS-staged MFMA: 64 rows/block x 256 thr, grid 1563 (~6 waves/SIMD),
// double-buffered 8KB x-tiles via global_load_lds width=16 (coalesced staging),
// XOR-swizzle on global SOURCE (linear LDS dest) + same XOR on ds_read_b128
// (2-way banks = free). Per step: stage(s+1) || 2 ds_read + hi/lo split + 3 MFMA.
#define G1_NBLK 1563   // ceil(100000/64)

__device__ inline void split8(const float4 a, const float4 b, short8v& hi, short8v& lo) {
    float f[8] = {a.x, a.y, a.z, a.w, b.x, b.y, b.z, b.w};
#pragma unroll
    for (int i = 0; i < 8; ++i) {
        unsigned int u = __float_as_uint(f[i]);
        unsigned int uh = u & 0xFFFF0000u;
        hi[i] = (short)(u >> 16);
        lo[i] = (short)f2bf(f[i] - __uint_as_float(uh));
    }
}

__global__ __launch_bounds__(256) void gemm1(const float* __restrict__ x,
        const uint4* __restrict__ wp, const float* __restrict__ dinv,
        unsigned short* __restrict__ m1s) {
    __shared__ float lds[2][2048];   // 2 x 8 KB: [64 rows][128 B], swizzled
    const int t = threadIdx.x, b = blockIdx.x;
    const int lane = t & 63, w = t >> 6;
    const int rowbase = b * 64;
    const char* xb = (const char*)x;

    // staging source addresses (j=0: rows 0-31, j=1: rows 32-63)
    // LDS byte (row*128 + u*16) holds global bytes (u*16)^((row&7)<<4) of the step's 128B
    size_t gbase[2], gtail[2];
#pragma unroll
    for (int j = 0; j < 2; ++j) {
        int i = j * 256 + t;
        int row = i >> 3;                              // 0..63
        int u = i & 7;
        int inner = (u * 16) ^ ((row & 7) << 4);       // bytes within 128
        int grow = rowbase + row; if (grow >= N_NODES) grow = 0;
        gbase[j] = (size_t)grow * 2000 + (size_t)inner;
        int tf = 480 + (inner >> 2);                   // tail float idx
        gtail[j] = (tf < 500) ? gbase[j] + 1920 : (size_t)0;  // k>=500 -> x[0] (B=0 there)
    }

    // compute-side ds_read offsets (wave w owns rows w*16 .. w*16+15)
    const int r16 = lane & 15, g = lane >> 4;
    const int lrow = w * 16 + r16;
    const int sw = (lrow & 7) << 4;
    const int off1 = lrow * 128 + ((g * 32) ^ sw);
    const int off2 = lrow * 128 + ((g * 32 + 16) ^ sw);

    f32x4v acc = {0.f, 0.f, 0.f, 0.f};

    // prologue: stage step 0 into buf 0
    gload16(xb + gbase[0], (void*)&lds[0][w * 256]);
    gload16(xb + gbase[1], (void*)&lds[0][1024 + w * 256]);
    __syncthreads();

    int cur = 0;
    for (int s = 0; s < 16; ++s) {
        if (s < 15) {   // stage s+1 into the other buffer (overlaps with compute)
            int sn = s + 1;
            size_t a0 = (sn < 15) ? gbase[0] + (size_t)sn * 128 : gtail[0];
            size_t a1 = (sn < 15) ? gbase[1] + (size_t)sn * 128 : gtail[1];
            gload16(xb + a0, (void*)&lds[cur ^ 1][w * 256]);
            gload16(xb + a1, (void*)&lds[cur ^ 1][1024 + w * 256]);
        }
        short8v bh = *reinterpret_cast<const short8v*>(&wp[s * 64 + lane]);
        short8v bl = *reinterpret_cast<const short8v*>(&wp[1024 + s * 64 + lane]);
        const char* lb = (const char*)&lds[cur][0];
        float4 fa = *(const float4*)(lb + off1);
        float4 fb = *(const float4*)(lb + off2);
        short8v ah, al;
        split8(fa, fb, ah, al);
        acc = __builtin_amdgcn_mfma_f32_16x16x32_bf16(ah, bh, acc, 0, 0, 0);
        acc = __builtin_amdgcn_mfma_f32_16x16x32_bf16(al, bh, acc, 0, 0, 0);
        acc = __builtin_amdgcn_mfma_f32_16x16x32_bf16(ah, bl, acc, 0, 0, 0);
        __syncthreads();   // drains stage(s+1) + guards buffer swap
        cur ^= 1;
    }

    // C/D layout: col = lane&15, row = (lane>>4)*4 + j (within wave's 16-row tile)
#pragma unroll
    for (int j = 0; j < 4; ++j) {
        int r = rowbase + w * 16 + g * 4 + j;
        if (r < N_NODES) m1s[(size_t)r * 16 + r16] = f2bf(acc[j] * dinv[r]);
    }
}

// -------- layer-1 aggregate (register owner-computes) + bias + ReLU + h@W2
// 4 lanes per node; lane q owns features 4q..4q+3; per edge one uint2 (8B);
// the 4 lanes' loads form one 32B row segment. NO atomics.
__global__ __launch_bounds__(512) void agg1(const unsigned int* __restrict__ sorted,
        const int* __restrict__ rowptr, const float* __restrict__ dinv,
        const unsigned short* __restrict__ m1s, const float* __restrict__ b1,
        const float* __restrict__ W2, unsigned short* __restrict__ m2s) {
    __shared__ float acc[BKT_SIZE * 17];
    __shared__ float sW2[N_HID * N_CLS];
    __shared__ float sb1[N_HID];
    int t = threadIdx.x, b = blockIdx.x;
    if (t < N_HID * N_CLS) sW2[t] = W2[t];
    if (t < N_HID) sb1[t] = b1[t];
    int n = t >> 2, q = t & 3;
    int g = b * BKT_SIZE + n;
    float a0 = 0.f, a1 = 0.f, a2 = 0.f, a3 = 0.f;
    if (g < N_NODES) {
        int beg = rowptr[g], end = rowptr[g + 1];
        int p = beg;
        for (; p + 1 < end; p += 2) {
            unsigned int s0 = sorted[p], s1 = sorted[p + 1];
            uint2 w0 = *(const uint2*)&m1s[(size_t)s0 * 16 + q * 4];
            uint2 w1 = *(const uint2*)&m1s[(size_t)s1 * 16 + q * 4];
            a0 += __uint_as_float(w0.x << 16);
            a1 += __uint_as_float(w0.x & 0xFFFF0000u);
            a2 += __uint_as_float(w0.y << 16);
            a3 += __uint_as_float(w0.y & 0xFFFF0000u);
            a0 += __uint_as_float(w1.x << 16);
            a1 += __uint_as_float(w1.x & 0xFFFF0000u);
            a2 += __uint_as_float(w1.y << 16);
            a3 += __uint_as_float(w1.y & 0xFFFF0000u);
        }
        if (p < end) {
            unsigned int s0 = sorted[p];
            uint2 w0 = *(const uint2*)&m1s[(size_t)s0 * 16 + q * 4];
            a0 += __uint_as_float(w0.x << 16);
            a1 += __uint_as_float(w0.x & 0xFFFF0000u);
            a2 += __uint_as_float(w0.y << 16);
            a3 += __uint_as_float(w0.y & 0xFFFF0000u);
        }
    }
    float* ap = &acc[n * 17 + q * 4];
    ap[0] = a0; ap[1] = a1; ap[2] = a2; ap[3] = a3;
    __syncthreads();
    // h = relu(dinv_g * (acc + m1s_g) + b1), in place (stride 17)
    for (int idx = t; idx < BKT_SIZE * 16; idx += 512) {
        int nn = idx >> 4, jj = idx & 15;
        int gg = b * BKT_SIZE + nn;
        if (gg < N_NODES) {
            float di = dinv[gg];
            float hv = di * (acc[nn * 17 + jj] + bf2f(m1s[(size_t)gg * 16 + jj])) + sb1[jj];
            acc[nn * 17 + jj] = hv > 0.f ? hv : 0.f;
        }
    }
    __syncthreads();
    // m2s = bf16(dinv_g * (h @ W2)), stride 8, slot 7 = 0 pad
    for (int idx = t; idx < BKT_SIZE * 8; idx += 512) {
        int nn = idx >> 3, cc = idx & 7;
        int gg = b * BKT_SIZE + nn;
        if (gg < N_NODES) {
            float sum = 0.f;
            if (cc < N_CLS) {
#pragma unroll
                for (int jj = 0; jj < N_HID; ++jj) sum += acc[nn * 17 + jj] * sW2[jj * 7 + cc];
                sum *= dinv[gg];
            }
            m2s[(size_t)gg * 8 + cc] = f2bf(sum);
        }
    }
}

// -------- layer-2 aggregate (register owner-computes) + bias + log-softmax
// 2 lanes per node; lane q owns slots 4q..4q+3 (slot 7 = pad). NO atomics.
__global__ __launch_bounds__(256) void agg2(const unsigned int* __restrict__ sorted,
        const int* __restrict__ rowptr, const float* __restrict__ dinv,
        const unsigned short* __restrict__ m2s, const float* __restrict__ b2,
        float* __restrict__ out) {
    __shared__ float acc[BKT_SIZE * 9];
    int t = threadIdx.x, b = blockIdx.x;
    int n = t >> 1, q = t & 1;
    int g = b * BKT_SIZE + n;
    float a0 = 0.f, a1 = 0.f, a2 = 0.f, a3 = 0.f;
    if (g < N_NODES) {
        int beg = rowptr[g], end = rowptr[g + 1];
        int p = beg;
        for (; p + 1 < end; p += 2) {
            unsigned int s0 = sorted[p], s1 = sorted[p + 1];
            uint2 w0 = *(const uint2*)&m2s[(size_t)s0 * 8 + q * 4];
            uint2 w1 = *(const uint2*)&m2s[(size_t)s1 * 8 + q * 4];
            a0 += __uint_as_float(w0.x << 16);
            a1 += __uint_as_float(w0.x & 0xFFFF0000u);
            a2 += __uint_as_float(w0.y << 16);
            a3 += __uint_as_float(w0.y & 0xFFFF0000u);
            a0 += __uint_as_float(w1.x << 16);
            a1 += __uint_as_float(w1.x & 0xFFFF0000u);
            a2 += __uint_as_float(w1.y << 16);
            a3 += __uint_as_float(w1.y & 0xFFFF0000u);
        }
        if (p < end) {
            unsigned int s0 = sorted[p];
            uint2 w0 = *(const uint2*)&m2s[(size_t)s0 * 8 + q * 4];
            a0 += __uint_as_float(w0.x << 16);
            a1 += __uint_as_float(w0.x & 0xFFFF0000u);
            a2 += __uint_as_float(w0.y << 16);
            a3 += __uint_as_float(w0.y & 0xFFFF0000u);
        }
    }
    float* ap = &acc[n * 9 + q * 4];
    ap[0] = a0; ap[1] = a1; ap[2] = a2; ap[3] = a3;
    __syncthreads();
    int j = t & 7;
    for (int pass = 0; pass < 4; ++pass) {
        int nn = (t >> 3) + pass * 32;
        int gg = b * BKT_SIZE + nn;
        bool valid = (gg < N_NODES) && (j < N_CLS);
        float v = -1e30f;
        if (valid) {
            float di = dinv[gg];
            v = di * (acc[nn * 9 + j] + bf2f(m2s[(size_t)gg * 8 + j])) + b2[j];
        }
        float mx = v;
#pragma unroll
        for (int off = 1; off < 8; off <<= 1) mx = fmaxf(mx, __shfl_xor(mx, off, 8));
        float ex = valid ? expf(v - mx) : 0.f;
        float sum = ex;
#pragma unroll
        for (int off = 1; off < 8; off <<= 1) sum += __shfl_xor(sum, off, 8);
        float ls = mx + logf(sum);
        if (valid) out[(size_t)gg * 7 + j] = v - ls;
    }
}

// ----------------------------------------------------------------
extern "C" void kernel_launch(void* const* d_in, const int* in_sizes, int n_in,
                              void* d_out, int out_size, void* d_ws, size_t ws_size,
                              hipStream_t stream) {
    const float* x  = (const float*)d_in[0];
    const int*   ei = (const int*)d_in[1];
    const float* W1 = (const float*)d_in[2];
    const float* b1 = (const float*)d_in[3];
    const float* W2 = (const float*)d_in[4];
    const float* b2 = (const float*)d_in[5];
    float* out = (float*)d_out;
    char*  wsb = (char*)d_ws;   // needs 32.0 MB

    const int* src = ei;               // edge_index[0]
    const int* dst = ei + N_EDGES;     // edge_index[1]

    float*          dinv   = (float*)wsb + OFF_DINV;
    int*            counts = (int*)wsb + OFF_COUNTS;
    int*            bsum   = (int*)wsb + OFF_BSUM;
    int*            rowptr = (int*)wsb + OFF_ROWP;
    unsigned int*   binned = (unsigned int*)wsb + OFF_BINNED;
    unsigned int*   sorted = (unsigned int*)wsb + OFF_SORTED;
    unsigned short* m1s    = (unsigned short*)(wsb + (size_t)OFF_M1S * 4);
    unsigned short* m2s    = (unsigned short*)(wsb + (size_t)OFF_M2S * 4);
    uint4*          wp     = (uint4*)binned;   // binned is dead after sortpass

    hist     <<<NBLK_BIN, 256, 0, stream>>>(dst, counts);
    scanA    <<<NBLK_SCANA, 256, 0, stream>>>(counts, bsum);
    scanB    <<<1, 1024, 0, stream>>>(bsum);
    binpass  <<<NBLK_BIN, 256, 0, stream>>>(src, dst, counts, bsum, binned);
    sortpass <<<NBKT, 512, 0, stream>>>(binned, counts, bsum, sorted, rowptr, dinv);
    wpack    <<<4, 256, 0, stream>>>(W1, wp);
    gemm1    <<<G1_NBLK, 256, 0, stream>>>(x, wp, dinv, m1s);
    agg1     <<<NBKT, 512, 0, stream>>>(sorted, rowptr, dinv, m1s, b1, W2, m2s);
    agg2     <<<NBKT, 256, 0, stream>>>(sorted, rowptr, dinv, m2s, b2, out);
}